// Round 7
// baseline (155.311 us; speedup 1.0000x reference)
//
#include <hip/hip_runtime.h>

#define Bn 8
#define Ln 256
#define Dn 128
#define Hn 6
#define En 32
#define WXROW (Hn + 2*Dn + En)   // 294

// -------- Kernel 1: gcn + out + n1/n2 --------
// grid = B * (L/2) = 1024 blocks, 256 threads -> 16 waves/CU resident
__global__ __launch_bounds__(256, 4) void k_gcn3(
    const float* __restrict__ x, const float* __restrict__ wadj,
    const float* __restrict__ W_w, const float* __restrict__ W_b,
    const float* __restrict__ Wx_w,
    const float* __restrict__ Wxx_w, const float* __restrict__ Wxx_b,
    float* __restrict__ out, float* __restrict__ n1_ws, float* __restrict__ n2_ws)
{
    __shared__ float adj_s[2][Ln];     // 2 KB
    __shared__ float part[8][2][Dn];   // 8 KB
    __shared__ float t_adj[2][Dn];     // 1 KB
    __shared__ float red[2][2][Dn];    // 4 KB (c-half, r, d)
    __shared__ float g_s[2][Dn];       // 1 KB

    const int t  = threadIdx.x;
    const int b  = blockIdx.x >> 7;
    const int i0 = (blockIdx.x & 127) * 2;

    // P1: adj_s[r][j] = mean_h wadj[b,h,i0+r,j]   (2 rows x 64 float4)
    if (t < 128) {
        const int r = t >> 6, j4 = t & 63;
        const float4* w4 = (const float4*)wadj;
        float4 s = {0.f, 0.f, 0.f, 0.f};
        #pragma unroll
        for (int h = 0; h < Hn; ++h) {
            const float4 v = w4[(((size_t)b * Hn + h) * Ln + i0 + r) * 64 + j4];
            s.x += v.x; s.y += v.y; s.z += v.z; s.w += v.w;
        }
        const float inv_h = 1.0f / 6.0f;
        s.x *= inv_h; s.y *= inv_h; s.z *= inv_h; s.w *= inv_h;
        *(float4*)&adj_s[r][j4 * 4] = s;
    }
    __syncthreads();

    // P2: partial t over j-slice q: part[q][r][d] = sum_{j in slice} adj[r][j]*x[b,j,d]
    {
        const int q  = t >> 5;      // 8 slices of 32 j
        const int d4 = t & 31;
        float4 a0 = {0.f, 0.f, 0.f, 0.f};
        float4 a1 = {0.f, 0.f, 0.f, 0.f};
        const float4* xp4 = (const float4*)(x + (size_t)b * Ln * Dn) + d4;
        const int j0 = q * 32;
        #pragma unroll
        for (int jj4 = 0; jj4 < 8; ++jj4) {
            const int j = j0 + jj4 * 4;
            const float4 xv0 = xp4[(size_t)(j + 0) * 32];
            const float4 xv1 = xp4[(size_t)(j + 1) * 32];
            const float4 xv2 = xp4[(size_t)(j + 2) * 32];
            const float4 xv3 = xp4[(size_t)(j + 3) * 32];
            const float c00 = adj_s[0][j + 0], c10 = adj_s[1][j + 0];
            const float c01 = adj_s[0][j + 1], c11 = adj_s[1][j + 1];
            const float c02 = adj_s[0][j + 2], c12 = adj_s[1][j + 2];
            const float c03 = adj_s[0][j + 3], c13 = adj_s[1][j + 3];
            a0.x = fmaf(c00, xv0.x, a0.x); a0.y = fmaf(c00, xv0.y, a0.y);
            a0.z = fmaf(c00, xv0.z, a0.z); a0.w = fmaf(c00, xv0.w, a0.w);
            a1.x = fmaf(c10, xv0.x, a1.x); a1.y = fmaf(c10, xv0.y, a1.y);
            a1.z = fmaf(c10, xv0.z, a1.z); a1.w = fmaf(c10, xv0.w, a1.w);
            a0.x = fmaf(c01, xv1.x, a0.x); a0.y = fmaf(c01, xv1.y, a0.y);
            a0.z = fmaf(c01, xv1.z, a0.z); a0.w = fmaf(c01, xv1.w, a0.w);
            a1.x = fmaf(c11, xv1.x, a1.x); a1.y = fmaf(c11, xv1.y, a1.y);
            a1.z = fmaf(c11, xv1.z, a1.z); a1.w = fmaf(c11, xv1.w, a1.w);
            a0.x = fmaf(c02, xv2.x, a0.x); a0.y = fmaf(c02, xv2.y, a0.y);
            a0.z = fmaf(c02, xv2.z, a0.z); a0.w = fmaf(c02, xv2.w, a0.w);
            a1.x = fmaf(c12, xv2.x, a1.x); a1.y = fmaf(c12, xv2.y, a1.y);
            a1.z = fmaf(c12, xv2.z, a1.z); a1.w = fmaf(c12, xv2.w, a1.w);
            a0.x = fmaf(c03, xv3.x, a0.x); a0.y = fmaf(c03, xv3.y, a0.y);
            a0.z = fmaf(c03, xv3.z, a0.z); a0.w = fmaf(c03, xv3.w, a0.w);
            a1.x = fmaf(c13, xv3.x, a1.x); a1.y = fmaf(c13, xv3.y, a1.y);
            a1.z = fmaf(c13, xv3.z, a1.z); a1.w = fmaf(c13, xv3.w, a1.w);
        }
        *(float4*)&part[q][0][d4 * 4] = a0;
        *(float4*)&part[q][1][d4 * 4] = a1;
    }
    __syncthreads();

    // P3: combine 8 slices: r = t>>7, d = t&127
    {
        const int r = t >> 7, d = t & 127;
        float s = 0.f;
        #pragma unroll
        for (int q = 0; q < 8; ++q) s += part[q][r][d];
        t_adj[r][d] = s;
    }
    __syncthreads();

    // P4: relu GEMM, c-split: s = t>>7 takes c in [s*64, s*64+64); d = t&127
    {
        const int s = t >> 7, d = t & 127, c0 = s * 64;
        const float4* wr = (const float4*)(W_w + (size_t)d * Dn + c0);
        float p0 = 0.f, p1 = 0.f;
        #pragma unroll
        for (int c4 = 0; c4 < 16; ++c4) {
            const float4 w  = wr[c4];
            const float4 u0 = *(const float4*)&t_adj[0][c0 + c4 * 4];
            const float4 u1 = *(const float4*)&t_adj[1][c0 + c4 * 4];
            p0 = fmaf(u0.x, w.x, p0); p0 = fmaf(u0.y, w.y, p0);
            p0 = fmaf(u0.z, w.z, p0); p0 = fmaf(u0.w, w.w, p0);
            p1 = fmaf(u1.x, w.x, p1); p1 = fmaf(u1.y, w.y, p1);
            p1 = fmaf(u1.z, w.z, p1); p1 = fmaf(u1.w, w.w, p1);
        }
        red[s][0][d] = p0;
        red[s][1][d] = p1;
    }
    __syncthreads();
    {
        const int r = t >> 7, d = t & 127;
        const float v = red[0][r][d] + red[1][r][d] + W_b[d];
        g_s[r][d] = fmaxf(v, 0.f);
    }
    __syncthreads();

    // P5: out GEMM, same split
    {
        const int s = t >> 7, d = t & 127, c0 = s * 64;
        const float4* wr = (const float4*)(Wxx_w + (size_t)d * Dn + c0);
        float p0 = 0.f, p1 = 0.f;
        #pragma unroll
        for (int c4 = 0; c4 < 16; ++c4) {
            const float4 w  = wr[c4];
            const float4 u0 = *(const float4*)&g_s[0][c0 + c4 * 4];
            const float4 u1 = *(const float4*)&g_s[1][c0 + c4 * 4];
            p0 = fmaf(u0.x, w.x, p0); p0 = fmaf(u0.y, w.y, p0);
            p0 = fmaf(u0.z, w.z, p0); p0 = fmaf(u0.w, w.w, p0);
            p1 = fmaf(u1.x, w.x, p1); p1 = fmaf(u1.y, w.y, p1);
            p1 = fmaf(u1.z, w.z, p1); p1 = fmaf(u1.w, w.w, p1);
        }
        red[s][0][d] = p0;
        red[s][1][d] = p1;
    }
    __syncthreads();
    {
        const int r = t >> 7, d = t & 127;
        const float v = red[0][r][d] + red[1][r][d] + Wxx_b[d];
        out[((size_t)b * Ln + (i0 + r)) * Dn + d] = v;
    }

    // P6: n1/n2: 2 rows x 12 = 24 dot-products of length 128 (g_s stable)
    if (t < 2 * 2 * Hn) {
        const int r  = t / (2 * Hn);
        const int kk = t % (2 * Hn);
        const int k  = (kk < Hn) ? kk : (kk - Hn);
        const bool isn2 = (kk >= Hn);
        const float* wrow = Wx_w + (size_t)k * WXROW + Hn + (isn2 ? Dn : 0);
        float acc = 0.f;
        #pragma unroll 8
        for (int c = 0; c < Dn; ++c)
            acc = fmaf(g_s[r][c], wrow[c], acc);
        const size_t idx = ((size_t)b * Hn + k) * Ln + (i0 + r);
        if (isn2) n2_ws[idx] = acc;
        else      n1_ws[idx] = acc;
    }
}

// -------- Kernel 2: new_adj (chunked LDS: 2 j-halves, 8 blocks/CU) --------
// grid = B*L blocks (b,i), 256 threads
#define EPAD 33
__global__ __launch_bounds__(256) void k_adj(
    const float* __restrict__ wadj, const float* __restrict__ e,
    const float* __restrict__ Wx_w, const float* __restrict__ Wx_b,
    const float* __restrict__ n1_ws, const float* __restrict__ n2_ws,
    float* __restrict__ new_adj)
{
    __shared__ float e_lds[128 * EPAD];  // 16.5 KB
    __shared__ float Wa_s[Hn][Hn];
    __shared__ float We_s[Hn][En];
    __shared__ float bias_n1[Hn];

    const int t = threadIdx.x;
    const int b = blockIdx.x >> 8;
    const int i = blockIdx.x & 255;

    if (t < Hn * Hn) {
        const int k = t / Hn, h = t % Hn;
        Wa_s[k][h] = Wx_w[(size_t)k * WXROW + h];
    }
    if (t >= 64 && t < 64 + Hn * En) {
        const int q = t - 64, k = q / En, c = q % En;
        We_s[k][c] = Wx_w[(size_t)k * WXROW + Hn + 2 * Dn + c];
    }
    if (t >= 32 && t < 32 + Hn) {
        const int k = t - 32;
        bias_n1[k] = Wx_b[k] + n1_ws[((size_t)b * Hn + k) * Ln + i];
    }

    const float4* ep4 = (const float4*)(e + (((size_t)b * Ln + i) * Ln) * En);
    const int s  = t >> 7;          // k-group: 0 -> k 0..2, 1 -> k 3..5
    const int jl = t & 127;         // local j within chunk

    #pragma unroll
    for (int cH = 0; cH < 2; ++cH) {
        __syncthreads();            // protect e_lds (also covers weight-LDS init)
        #pragma unroll
        for (int p = 0; p < 4; ++p) {
            const int idx = t + p * 256;
            const float4 v = ep4[cH * 1024 + idx];
            const int j = idx >> 3;
            const int c = (idx & 7) * 4;
            float* dst = &e_lds[j * EPAD + c];
            dst[0] = v.x; dst[1] = v.y; dst[2] = v.z; dst[3] = v.w;
        }
        __syncthreads();

        const int j = cH * 128 + jl;

        float wv[Hn];
        #pragma unroll
        for (int h = 0; h < Hn; ++h)
            wv[h] = wadj[(((size_t)b * Hn + h) * Ln + i) * Ln + j];

        const float* ev = &e_lds[jl * EPAD];

        #pragma unroll
        for (int kq = 0; kq < 3; ++kq) {
            const int k = s * 3 + kq;
            float acc = bias_n1[k] + n2_ws[((size_t)b * Hn + k) * Ln + j];
            #pragma unroll
            for (int h = 0; h < Hn; ++h)
                acc = fmaf(wv[h], Wa_s[k][h], acc);
            #pragma unroll
            for (int c = 0; c < En; ++c)
                acc = fmaf(ev[c], We_s[k][c], acc);
            new_adj[(((size_t)b * Hn + k) * Ln + i) * Ln + j] = acc;
        }
    }
}

extern "C" void kernel_launch(void* const* d_in, const int* in_sizes, int n_in,
                              void* d_out, int out_size, void* d_ws, size_t ws_size,
                              hipStream_t stream) {
    const float* x      = (const float*)d_in[0];
    const float* wadj   = (const float*)d_in[1];
    const float* e      = (const float*)d_in[2];
    const float* W_w    = (const float*)d_in[3];
    const float* W_b    = (const float*)d_in[4];
    const float* Wx_w   = (const float*)d_in[5];
    const float* Wx_b   = (const float*)d_in[6];
    const float* Wxx_w  = (const float*)d_in[7];
    const float* Wxx_b  = (const float*)d_in[8];

    float* out      = (float*)d_out;                   // (B,L,D)
    float* new_adj  = out + (size_t)Bn * Ln * Dn;      // (B,H,L,L)

    float* n1_ws = (float*)d_ws;                       // (B,H,L)
    float* n2_ws = n1_ws + (size_t)Bn * Hn * Ln;       // (B,H,L)

    k_gcn3<<<Bn * (Ln / 2), 256, 0, stream>>>(x, wadj, W_w, W_b, Wx_w,
                                              Wxx_w, Wxx_b, out, n1_ws, n2_ws);
    k_adj<<<Bn * Ln, 256, 0, stream>>>(wadj, e, Wx_w, Wx_b, n1_ws, n2_ws, new_adj);
}

// Round 8
// 147.396 us; speedup vs baseline: 1.0537x; 1.0537x over previous
//
#include <hip/hip_runtime.h>

#define Bn 8
#define Ln 256
#define Dn 128
#define Hn 6
#define En 32
#define WXROW (Hn + 2*Dn + En)   // 294
#define ROWS 4                   // i-rows per k_gcn block

// -------- Kernel 1: gcn + out + n1/n2 (r4 structure + cross-phase prefetch) ----
// grid = B * (L/ROWS) = 512 blocks, 256 threads
__global__ __launch_bounds__(256) void k_gcn(
    const float* __restrict__ x, const float* __restrict__ wadj,
    const float* __restrict__ W_w, const float* __restrict__ W_b,
    const float* __restrict__ Wx_w,
    const float* __restrict__ Wxx_w, const float* __restrict__ Wxx_b,
    float* __restrict__ out, float* __restrict__ n1_ws, float* __restrict__ n2_ws)
{
    __shared__ float adj[ROWS][Ln];        // 4 KB
    __shared__ float part[8][ROWS][Dn];    // 16 KB
    __shared__ float t_s[ROWS][Dn];        // 2 KB
    __shared__ float g_s[ROWS][Dn];        // 2 KB

    const int t  = threadIdx.x;
    const int b  = blockIdx.x >> 6;
    const int i0 = (blockIdx.x & 63) * ROWS;

    const int q  = t >> 5;                 // j-slice (8 of 32 js)
    const int d4 = t & 31;                 // float4 column
    const float4* xp4 = (const float4*)(x + (size_t)b * Ln * Dn) + d4;
    const int j0 = q * 32;

    // --- prefetch first 8 x rows of this thread's j-slice (independent of P1)
    float4 xpre[8];
    #pragma unroll
    for (int p = 0; p < 8; ++p)
        xpre[p] = xp4[(size_t)(j0 + p) * 32];

    // P1: adj[r][j] = mean_h wadj[b,h,i0+r,j]   (overlaps with xpre in flight)
    {
        const int r  = t >> 6;
        const int j4 = t & 63;
        const float4* w4 = (const float4*)wadj;
        float4 s = {0.f, 0.f, 0.f, 0.f};
        #pragma unroll
        for (int h = 0; h < Hn; ++h) {
            const float4 v = w4[(((size_t)b * Hn + h) * Ln + (i0 + r)) * 64 + j4];
            s.x += v.x; s.y += v.y; s.z += v.z; s.w += v.w;
        }
        const float inv_h = 1.0f / 6.0f;
        s.x *= inv_h; s.y *= inv_h; s.z *= inv_h; s.w *= inv_h;
        ((float4*)&adj[0][0])[r * 64 + j4] = s;
    }
    __syncthreads();

    // P2: part[q][r][d] = sum_{j in slice} adj[r][j]*x[b,j,d]
    {
        float4 acc[ROWS];
        #pragma unroll
        for (int r = 0; r < ROWS; ++r) acc[r] = {0.f, 0.f, 0.f, 0.f};
        const float4* adj4 = (const float4*)&adj[0][0];

        #pragma unroll
        for (int blk4 = 0; blk4 < 8; ++blk4) {
            const int j = j0 + blk4 * 4;
            float4 xv0, xv1, xv2, xv3;
            if (blk4 < 2) {
                xv0 = xpre[blk4 * 4 + 0]; xv1 = xpre[blk4 * 4 + 1];
                xv2 = xpre[blk4 * 4 + 2]; xv3 = xpre[blk4 * 4 + 3];
            } else {
                xv0 = xp4[(size_t)(j + 0) * 32];
                xv1 = xp4[(size_t)(j + 1) * 32];
                xv2 = xp4[(size_t)(j + 2) * 32];
                xv3 = xp4[(size_t)(j + 3) * 32];
            }
            #pragma unroll
            for (int r = 0; r < ROWS; ++r) {
                const float4 a = adj4[r * 64 + (j >> 2)];
                float4 v = acc[r];
                v.x = fmaf(a.x, xv0.x, v.x); v.y = fmaf(a.x, xv0.y, v.y);
                v.z = fmaf(a.x, xv0.z, v.z); v.w = fmaf(a.x, xv0.w, v.w);
                v.x = fmaf(a.y, xv1.x, v.x); v.y = fmaf(a.y, xv1.y, v.y);
                v.z = fmaf(a.y, xv1.z, v.z); v.w = fmaf(a.y, xv1.w, v.w);
                v.x = fmaf(a.z, xv2.x, v.x); v.y = fmaf(a.z, xv2.y, v.y);
                v.z = fmaf(a.z, xv2.z, v.z); v.w = fmaf(a.z, xv2.w, v.w);
                v.x = fmaf(a.w, xv3.x, v.x); v.y = fmaf(a.w, xv3.y, v.y);
                v.z = fmaf(a.w, xv3.z, v.z); v.w = fmaf(a.w, xv3.w, v.w);
                acc[r] = v;
            }
        }
        #pragma unroll
        for (int r = 0; r < ROWS; ++r)
            ((float4*)&part[q][r][0])[d4] = acc[r];
    }
    __syncthreads();

    const int dd = t & 127;
    const int ss = t >> 7;

    // --- prefetch first quarter of this thread's W_w row (consumed in P4)
    float4 wpre[8];
    {
        const float4* wr = (const float4*)(W_w + (size_t)dd * Dn);
        #pragma unroll
        for (int p = 0; p < 8; ++p) wpre[p] = wr[p];
    }

    // P3: combine 8 j-slices
    {
        #pragma unroll
        for (int rq = 0; rq < 2; ++rq) {
            const int r = ss + rq * 2;
            float s = 0.f;
            #pragma unroll
            for (int qq = 0; qq < 8; ++qq) s += part[qq][r][dd];
            t_s[r][dd] = s;
        }
    }
    __syncthreads();

    // P4: relu GEMM for r in {ss, ss+2}
    {
        const int r0 = ss, r1 = ss + 2;
        float a0 = W_b[dd], a1 = a0;
        const float4* wr = (const float4*)(W_w + (size_t)dd * Dn);
        const float4* t0 = (const float4*)&t_s[r0][0];
        const float4* t1 = (const float4*)&t_s[r1][0];
        #pragma unroll
        for (int c4 = 0; c4 < Dn / 4; ++c4) {
            const float4 w = (c4 < 8) ? wpre[c4] : wr[c4];
            const float4 u0 = t0[c4];
            const float4 u1 = t1[c4];
            a0 = fmaf(u0.x, w.x, a0); a0 = fmaf(u0.y, w.y, a0);
            a0 = fmaf(u0.z, w.z, a0); a0 = fmaf(u0.w, w.w, a0);
            a1 = fmaf(u1.x, w.x, a1); a1 = fmaf(u1.y, w.y, a1);
            a1 = fmaf(u1.z, w.z, a1); a1 = fmaf(u1.w, w.w, a1);
        }
        g_s[r0][dd] = fmaxf(a0, 0.f);
        g_s[r1][dd] = fmaxf(a1, 0.f);
    }
    // --- prefetch first quarter of Wxx row while g_s finishes
    {
        const float4* wr = (const float4*)(Wxx_w + (size_t)dd * Dn);
        #pragma unroll
        for (int p = 0; p < 8; ++p) wpre[p] = wr[p];
    }
    __syncthreads();

    // P5: out GEMM for r in {ss, ss+2}
    {
        const int r0 = ss, r1 = ss + 2;
        float a0 = Wxx_b[dd], a1 = a0;
        const float4* wr = (const float4*)(Wxx_w + (size_t)dd * Dn);
        const float4* g0 = (const float4*)&g_s[r0][0];
        const float4* g1 = (const float4*)&g_s[r1][0];
        #pragma unroll
        for (int c4 = 0; c4 < Dn / 4; ++c4) {
            const float4 w = (c4 < 8) ? wpre[c4] : wr[c4];
            const float4 u0 = g0[c4];
            const float4 u1 = g1[c4];
            a0 = fmaf(u0.x, w.x, a0); a0 = fmaf(u0.y, w.y, a0);
            a0 = fmaf(u0.z, w.z, a0); a0 = fmaf(u0.w, w.w, a0);
            a1 = fmaf(u1.x, w.x, a1); a1 = fmaf(u1.y, w.y, a1);
            a1 = fmaf(u1.z, w.z, a1); a1 = fmaf(u1.w, w.w, a1);
        }
        out[((size_t)b * Ln + (i0 + r0)) * Dn + dd] = a0;
        out[((size_t)b * Ln + (i0 + r1)) * Dn + dd] = a1;
    }

    // P6: n1/n2 (reads g_s, stable since P4's barrier)
    if (t < ROWS * 2 * Hn) {
        const int r  = t / (2 * Hn);
        const int kk = t % (2 * Hn);
        const int k  = (kk < Hn) ? kk : (kk - Hn);
        const bool isn2 = (kk >= Hn);
        const float* wrow = Wx_w + (size_t)k * WXROW + Hn + (isn2 ? Dn : 0);
        float acc = 0.f;
        #pragma unroll 8
        for (int c = 0; c < Dn; ++c)
            acc = fmaf(g_s[r][c], wrow[c], acc);
        const size_t idx = ((size_t)b * Hn + k) * Ln + (i0 + r);
        if (isn2) n2_ws[idx] = acc;
        else      n1_ws[idx] = acc;
    }
}

// -------- Kernel 2: new_adj — double-buffered halves, 8 blocks/CU ----------
// grid = B*L blocks (b,i), 256 threads
#define EPAD 33
__global__ __launch_bounds__(256) void k_adj(
    const float* __restrict__ wadj, const float* __restrict__ e,
    const float* __restrict__ Wx_w, const float* __restrict__ Wx_b,
    const float* __restrict__ n1_ws, const float* __restrict__ n2_ws,
    float* __restrict__ new_adj)
{
    __shared__ float e_lds[128 * EPAD];  // 16.9 KB
    __shared__ float Wa_s[Hn][Hn];
    __shared__ float We_s[Hn][En];
    __shared__ float bias_n1[Hn];

    const int t = threadIdx.x;
    const int b = blockIdx.x >> 8;
    const int i = blockIdx.x & 255;

    const float4* ep4 = (const float4*)(e + (((size_t)b * Ln + i) * Ln) * En);

    // issue BOTH halves' global loads up front (8 float4 in flight / thread)
    float4 A[4], Bv[4];
    #pragma unroll
    for (int p = 0; p < 4; ++p) A[p]  = ep4[t + p * 256];
    #pragma unroll
    for (int p = 0; p < 4; ++p) Bv[p] = ep4[1024 + t + p * 256];

    // small weights -> LDS (loads overlap with A/B in flight)
    if (t < Hn * Hn) {
        const int k = t / Hn, h = t % Hn;
        Wa_s[k][h] = Wx_w[(size_t)k * WXROW + h];
    }
    if (t >= 64 && t < 64 + Hn * En) {
        const int q = t - 64, k = q / En, c = q % En;
        We_s[k][c] = Wx_w[(size_t)k * WXROW + Hn + 2 * Dn + c];
    }
    if (t >= 32 && t < 32 + Hn) {
        const int k = t - 32;
        bias_n1[k] = Wx_b[k] + n1_ws[((size_t)b * Hn + k) * Ln + i];
    }

    // stage half0 (waits only on A; B remains in flight)
    #pragma unroll
    for (int p = 0; p < 4; ++p) {
        const int idx = t + p * 256;
        const int j = idx >> 3;
        const int c = (idx & 7) * 4;
        float* dst = &e_lds[j * EPAD + c];
        dst[0] = A[p].x; dst[1] = A[p].y; dst[2] = A[p].z; dst[3] = A[p].w;
    }
    __syncthreads();

    const int s  = t >> 7;          // k-group: 0 -> k 0..2, 1 -> k 3..5
    const int jl = t & 127;

    #pragma unroll
    for (int cH = 0; cH < 2; ++cH) {
        const int j = cH * 128 + jl;

        float wv[Hn];
        #pragma unroll
        for (int h = 0; h < Hn; ++h)
            wv[h] = wadj[(((size_t)b * Hn + h) * Ln + i) * Ln + j];

        float n2v[3];
        #pragma unroll
        for (int kq = 0; kq < 3; ++kq)
            n2v[kq] = n2_ws[((size_t)b * Hn + s * 3 + kq) * Ln + j];

        const float* ev = &e_lds[jl * EPAD];
        float evr[En];
        #pragma unroll
        for (int c = 0; c < En; ++c) evr[c] = ev[c];

        #pragma unroll
        for (int kq = 0; kq < 3; ++kq) {
            const int k = s * 3 + kq;
            float acc = bias_n1[k] + n2v[kq];
            #pragma unroll
            for (int h = 0; h < Hn; ++h)
                acc = fmaf(wv[h], Wa_s[k][h], acc);
            #pragma unroll
            for (int c = 0; c < En; ++c)
                acc = fmaf(evr[c], We_s[k][c], acc);
            new_adj[(((size_t)b * Hn + k) * Ln + i) * Ln + j] = acc;
        }

        if (cH == 0) {
            __syncthreads();   // everyone done reading half0
            #pragma unroll
            for (int p = 0; p < 4; ++p) {
                const int idx = t + p * 256;
                const int jj = idx >> 3;
                const int c = (idx & 7) * 4;
                float* dst = &e_lds[jj * EPAD + c];
                dst[0] = Bv[p].x; dst[1] = Bv[p].y;
                dst[2] = Bv[p].z; dst[3] = Bv[p].w;
            }
            __syncthreads();
        }
    }
}

extern "C" void kernel_launch(void* const* d_in, const int* in_sizes, int n_in,
                              void* d_out, int out_size, void* d_ws, size_t ws_size,
                              hipStream_t stream) {
    const float* x      = (const float*)d_in[0];
    const float* wadj   = (const float*)d_in[1];
    const float* e      = (const float*)d_in[2];
    const float* W_w    = (const float*)d_in[3];
    const float* W_b    = (const float*)d_in[4];
    const float* Wx_w   = (const float*)d_in[5];
    const float* Wx_b   = (const float*)d_in[6];
    const float* Wxx_w  = (const float*)d_in[7];
    const float* Wxx_b  = (const float*)d_in[8];

    float* out      = (float*)d_out;                   // (B,L,D)
    float* new_adj  = out + (size_t)Bn * Ln * Dn;      // (B,H,L,L)

    float* n1_ws = (float*)d_ws;                       // (B,H,L)
    float* n2_ws = n1_ws + (size_t)Bn * Hn * Ln;       // (B,H,L)

    k_gcn<<<Bn * (Ln / ROWS), 256, 0, stream>>>(x, wadj, W_w, W_b, Wx_w,
                                                Wxx_w, Wxx_b, out, n1_ws, n2_ws);
    k_adj<<<Bn * Ln, 256, 0, stream>>>(wadj, e, Wx_w, Wx_b, n1_ws, n2_ws, new_adj);
}